// Round 7
// baseline (253.820 us; speedup 1.0000x reference)
//
#include <hip/hip_runtime.h>
#include <hip/hip_bf16.h>

// B=32, C=128, HW=4096.
//   E = [wB;wV]@x + bias ; expB/expV = exp(E) (bf16) ; ZB/ZV row sums
//   T[i,c] = sum_n expB[i,n]*x[c,n]
//   G[i,j] = ((T[i,:].wA[j,:])/ZB_i + bA[j]) / (4096*ZV_i)
//   out[j,n] = sum_i expV[i,n]*G[i,j]
// R7: regrid the tail. R6: k1=72us (frozen this round), but k3b+k4 ~ 160us
//   unprofiled; occupancy arithmetic: k3b was 256 blocks = 1 block/CU = 4
//   waves/CU (!), k4 1024 blocks x 4 waves w/ 35KB LDS. Now k4 = 2048 blocks,
//   64-n tiles, 17.4KB LDS, (256,6) cap 85 (~70 needed); k3b = 1024 blocks,
//   16jx32i tiles, 6.9KB LDS. Numerics unchanged (same summation orders).

#define B_  32
#define C_  128
#define HW_ 4096

typedef __attribute__((ext_vector_type(8))) __bf16 bf16x8;
typedef __attribute__((ext_vector_type(4))) float f32x4;

__device__ __forceinline__ unsigned int bf_rne(float f) {   // bf16 bits (RNE)
    unsigned int u = __float_as_uint(f);
    return (u + 0x7fffu + ((u >> 16) & 1u)) >> 16;
}
__device__ __forceinline__ float bf_hi(float f) {           // RNE-to-bf16, as fp32
    unsigned int u = __float_as_uint(f);
    return __uint_as_float((u + 0x7fffu + ((u >> 16) & 1u)) & 0xffff0000u);
}

// ---------------------------------------------------------------------------
// k0: split Wcat=[wB;wV] (256x128 fp32) into bf16 hi/lo arrays. grid 32x256.
__global__ __launch_bounds__(256) void k0_prep(
    const float* __restrict__ wB, const float* __restrict__ wV,
    unsigned short* __restrict__ Wh, unsigned short* __restrict__ Wl)
{
    int g = blockIdx.x * 256 + threadIdx.x;      // 0..8191 float4s
    int row = g >> 5, c4 = (g & 31) << 2;
    const float* src = (row < 128) ? &wB[row * 128] : &wV[(row - 128) * 128];
    float4 v = *(const float4*)&src[c4];
    float vv[4] = {v.x, v.y, v.z, v.w};
    unsigned int h[4], l[4];
#pragma unroll
    for (int e = 0; e < 4; ++e) {
        float hf = bf_hi(vv[e]);
        h[e] = __float_as_uint(hf) >> 16;
        l[e] = bf_rne(vv[e] - hf);
    }
    *(uint2*)&Wh[row * 128 + c4] = make_uint2(h[0] | (h[1] << 16), h[2] | (h[3] << 16));
    *(uint2*)&Wl[row * 128 + c4] = make_uint2(l[0] | (l[1] << 16), l[2] | (l[3] << 16));
}

// ---------------------------------------------------------------------------
// k1_fused: E-GEMM + exp + Z + T-GEMM + expVT copy-out. grid (16, 32),
// 1024 thr = 16 waves. (unchanged from R6: 72us, VGPR=64, no spill)
__global__ __launch_bounds__(1024, 1) void k1_fused(
    const float* __restrict__ x,
    const unsigned short* __restrict__ Wh, const unsigned short* __restrict__ Wl,
    const float* __restrict__ bB, const float* __restrict__ bV,
    unsigned short* __restrict__ expVT, float* __restrict__ T_part,
    float* __restrict__ Zcat)
{
    __shared__ unsigned short XT_h[32 * 136];   // [n][c] pitch 136 (E B-operand)
    __shared__ unsigned short XT_l[32 * 136];
    __shared__ unsigned short XN_h[128 * 40];   // [c][n] pitch 40 (T B-operand)
    __shared__ unsigned short XN_l[128 * 40];
    __shared__ unsigned short EBs[128 * 40];    // expB [i][n] pitch 40 (T A-operand)
    __shared__ unsigned short EVs[32 * 136];    // expV [n][i] pitch 136 (copy-out)
    __shared__ float bias_s[256];

    const int t = threadIdx.x;
    const int lane = t & 63, w = t >> 6;        // w = 0..15
    const int col16 = lane & 15, quad = lane >> 4;
    const int b = blockIdx.y;
    const int n0 = blockIdx.x * 256;
    const float* xb = x + (size_t)b * C_ * HW_;

    // staging pattern A (for XT): thread owns 4 c (cq0*4+cc) at one n (snA)
    const int snA = t & 31, cq0 = t >> 5;       // cq0 = 0..31
    // staging pattern B (for XN): thread owns 1 c row (scB), 4 n (sqB..+3)
    const int scB = t >> 3, sqB = (t & 7) * 4;

    const int rowbase = w * 16;                 // E rows for this wave (0..255)
    const int lbase = (w & 7) * 16;             // row base within 128-row projection
    const int boff = (w < 8) ? 0 : 128;
    const int mh = (w >> 3) * 64;               // T tile: i-half
    const int nh = (w & 7) * 16;                // T tile: c-sixteenth

    if (t < 256) bias_s[t] = (t < 128) ? bB[t] : bV[t - 128];

    f32x4 tacc[4];
    float zacc[4];
#pragma unroll
    for (int i = 0; i < 4; ++i) { tacc[i] = (f32x4){0.f,0.f,0.f,0.f}; zacc[i] = 0.f; }

    // prefetch subtile 0, both patterns
    float xrA[4], xrB[4];
#pragma unroll
    for (int cc = 0; cc < 4; ++cc)
        xrA[cc] = xb[(size_t)(cq0 * 4 + cc) * HW_ + n0 + snA];
    *(float4*)xrB = *(const float4*)&xb[(size_t)scB * HW_ + n0 + sqB];

    for (int st = 0; st < 8; ++st) {
        // convert pattern A (pre-barrier: overlaps wait)
        unsigned int ha[4], la[4];
#pragma unroll
        for (int e = 0; e < 4; ++e) {
            float hf = bf_hi(xrA[e]);
            ha[e] = __float_as_uint(hf) >> 16;
            la[e] = bf_rne(xrA[e] - hf);
        }
        __syncthreads();   // B1: previous subtile's T-GEMM reads / copy-out done
        *(uint2*)&XT_h[snA * 136 + cq0 * 4] = make_uint2(ha[0] | (ha[1] << 16), ha[2] | (ha[3] << 16));
        *(uint2*)&XT_l[snA * 136 + cq0 * 4] = make_uint2(la[0] | (la[1] << 16), la[2] | (la[3] << 16));
        {
            unsigned int hb[4], lb[4];
#pragma unroll
            for (int e = 0; e < 4; ++e) {
                float hf = bf_hi(xrB[e]);
                hb[e] = __float_as_uint(hf) >> 16;
                lb[e] = bf_rne(xrB[e] - hf);
            }
            *(uint2*)&XN_h[scB * 40 + sqB] = make_uint2(hb[0] | (hb[1] << 16), hb[2] | (hb[3] << 16));
            *(uint2*)&XN_l[scB * 40 + sqB] = make_uint2(lb[0] | (lb[1] << 16), lb[2] | (lb[3] << 16));
        }
        __syncthreads();   // B2: XT/XN visible
        // prefetch next subtile (overlaps E/T compute)
        if (st < 7) {
            int ns2 = n0 + (st + 1) * 32;
#pragma unroll
            for (int cc = 0; cc < 4; ++cc)
                xrA[cc] = xb[(size_t)(cq0 * 4 + cc) * HW_ + ns2 + snA];
            *(float4*)xrB = *(const float4*)&xb[(size_t)scB * HW_ + ns2 + sqB];
        }

        // --- E-GEMM: wave computes rows rowbase..+15 x 32 n, K=128 (c), 3 terms
        f32x4 e0 = (f32x4){0.f,0.f,0.f,0.f}, e1 = (f32x4){0.f,0.f,0.f,0.f};
#pragma unroll
        for (int ks = 0; ks < 4; ++ks) {
            int kc = ks * 32 + quad * 8;
            bf16x8 xh0 = *(const bf16x8*)&XT_h[col16 * 136 + kc];
            bf16x8 xl0 = *(const bf16x8*)&XT_l[col16 * 136 + kc];
            bf16x8 xh1 = *(const bf16x8*)&XT_h[(16 + col16) * 136 + kc];
            bf16x8 xl1 = *(const bf16x8*)&XT_l[(16 + col16) * 136 + kc];
            int row = rowbase + col16;
            bf16x8 wh = *(const bf16x8*)&Wh[row * 128 + kc];
            bf16x8 wl = *(const bf16x8*)&Wl[row * 128 + kc];
            e0 = __builtin_amdgcn_mfma_f32_16x16x32_bf16(wh, xh0, e0, 0, 0, 0);
            e0 = __builtin_amdgcn_mfma_f32_16x16x32_bf16(wh, xl0, e0, 0, 0, 0);
            e0 = __builtin_amdgcn_mfma_f32_16x16x32_bf16(wl, xh0, e0, 0, 0, 0);
            e1 = __builtin_amdgcn_mfma_f32_16x16x32_bf16(wh, xh1, e1, 0, 0, 0);
            e1 = __builtin_amdgcn_mfma_f32_16x16x32_bf16(wh, xl1, e1, 0, 0, 0);
            e1 = __builtin_amdgcn_mfma_f32_16x16x32_bf16(wl, xh1, e1, 0, 0, 0);
        }

        // --- epilogue: exp, Z accumulate, expB->EBs [i][n] / expV->EVs [n][i]
#pragma unroll
        for (int r = 0; r < 4; ++r) {
            int lrow = lbase + quad * 4 + r;     // 0..127 within projection
            float bb = bias_s[boff + lrow];
            float v0 = __expf(e0[r] + bb);
            float v1 = __expf(e1[r] + bb);
            zacc[r] += v0 + v1;
            if (w < 8) {
                EBs[lrow * 40 + col16]      = (unsigned short)bf_rne(v0);
                EBs[lrow * 40 + 16 + col16] = (unsigned short)bf_rne(v1);
            } else {
                EVs[col16 * 136 + lrow]        = (unsigned short)bf_rne(v0);
                EVs[(16 + col16) * 136 + lrow] = (unsigned short)bf_rne(v1);
            }
        }
        __syncthreads();   // B3: EBs/EVs ready (XN still valid from B2)

        // --- T-GEMM: K=32 (this subtile), wave tile 64 i x 16 c
        {
            int c = nh + col16;
            bf16x8 bh = *(const bf16x8*)&XN_h[c * 40 + quad * 8];
            bf16x8 bl = *(const bf16x8*)&XN_l[c * 40 + quad * 8];
#pragma unroll
            for (int mt = 0; mt < 4; ++mt) {
                bf16x8 a = *(const bf16x8*)&EBs[(mh + mt * 16 + col16) * 40 + quad * 8];
                tacc[mt] = __builtin_amdgcn_mfma_f32_16x16x32_bf16(a, bh, tacc[mt], 0, 0, 0);
                tacc[mt] = __builtin_amdgcn_mfma_f32_16x16x32_bf16(a, bl, tacc[mt], 0, 0, 0);
            }
        }
        // --- expVT copy-out (32 n x 128 i), one uint2 (4 bf16) per thread
        {
            int nl = t >> 5, io = (t & 31) * 4;
            *(uint2*)&expVT[((size_t)b * HW_ + n0 + st * 32 + nl) * 128 + io] =
                *(const uint2*)&EVs[nl * 136 + io];
        }
    }

    // T_part store (no atomics): chunk = blockIdx.x
    float* Tp = T_part + (((size_t)blockIdx.x * B_) + b) * 128 * 128;
#pragma unroll
    for (int mt = 0; mt < 4; ++mt)
#pragma unroll
        for (int r = 0; r < 4; ++r)
            Tp[(mh + mt * 16 + quad * 4 + r) * 128 + nh + col16] = tacc[mt][r];

    // Z atomics (one per row, reduced across col16 lanes first)
#pragma unroll
    for (int r = 0; r < 4; ++r) {
        float rs = zacc[r];
        rs += __shfl_xor(rs, 1, 16);
        rs += __shfl_xor(rs, 2, 16);
        rs += __shfl_xor(rs, 4, 16);
        rs += __shfl_xor(rs, 8, 16);
        if (col16 == 0)
            atomicAdd(&Zcat[b * 256 + boff + lbase + quad * 4 + r], rs);
    }
}

// ---------------------------------------------------------------------------
// k3b: G transposed + 2-way bf16 split; sums T_part inline during staging.
// grid (32, 32) = 1024 blocks (was 256 = 1 block/CU). Tiles 16 j x 32 i.
__global__ __launch_bounds__(256) void k3b_G(
    const float* __restrict__ T_part, const float* __restrict__ wA,
    const float* __restrict__ bA, const float* __restrict__ Zcat,
    unsigned short* __restrict__ Gth, unsigned short* __restrict__ Gtm, int np)
{
    const int t = threadIdx.x;
    const int tx = t & 15, ty = t >> 4;
    const int b = blockIdx.y;
    const int jb = (blockIdx.x >> 2) * 16;     // 8 j-tiles of 16
    const int ib = (blockIdx.x & 3) * 32;      // 4 i-tiles of 32

    __shared__ float Ts[32][36];
    __shared__ float Wa[16][36];

    float acc[2] = {0.f, 0.f};

    for (int c0 = 0; c0 < 128; c0 += 32) {
        __syncthreads();
        {
            int r = t >> 3, kq = (t & 7) << 2;
            float4 s = make_float4(0.f, 0.f, 0.f, 0.f);
            for (int p = 0; p < np; ++p) {
                float4 v = *(const float4*)&T_part[(((size_t)p * B_ + b) * 128 + ib + r) * 128 + c0 + kq];
                s.x += v.x; s.y += v.y; s.z += v.z; s.w += v.w;
            }
            *(float4*)&Ts[r][kq] = s;
        }
        if (t < 128) {
            int r = t >> 3, kq = (t & 7) << 2;
            *(float4*)&Wa[r][kq] = *(const float4*)&wA[(jb + r) * 128 + c0 + kq];
        }
        __syncthreads();
#pragma unroll
        for (int k = 0; k < 32; k += 4) {
            float4 wv  = *(const float4*)&Wa[ty][k];
            float4 tv0 = *(const float4*)&Ts[tx][k];
            float4 tv1 = *(const float4*)&Ts[16 + tx][k];
            acc[0] = fmaf(wv.x, tv0.x, acc[0]);
            acc[0] = fmaf(wv.y, tv0.y, acc[0]);
            acc[0] = fmaf(wv.z, tv0.z, acc[0]);
            acc[0] = fmaf(wv.w, tv0.w, acc[0]);
            acc[1] = fmaf(wv.x, tv1.x, acc[1]);
            acc[1] = fmaf(wv.y, tv1.y, acc[1]);
            acc[1] = fmaf(wv.z, tv1.z, acc[1]);
            acc[1] = fmaf(wv.w, tv1.w, acc[1]);
        }
    }
    const float* ZB = Zcat + b * 256;
    const float* ZV = ZB + 128;
    {
        int j = jb + ty;
        float bj = bA[j];
#pragma unroll
        for (int ii = 0; ii < 2; ++ii) {
            int i = ib + ii * 16 + tx;
            float g = (acc[ii] / ZB[i] + bj) / (4096.f * ZV[i]);
            float h = bf_hi(g);  float r1 = g - h;
            float m = bf_hi(r1);
            size_t o = ((size_t)b * 128 + j) * 128 + i;
            Gth[o] = (unsigned short)(__float_as_uint(h) >> 16);
            Gtm[o] = (unsigned short)(__float_as_uint(m) >> 16);
        }
    }
}

// ---------------------------------------------------------------------------
// k4: out[b,j,n] = sum_i expVT[n][i] * Gt(j,i)  (MFMA, 2-term G split).
// grid (64, 32) = 2048 blocks, 64-n tiles, 17.4KB LDS, (256,6) cap 85 VGPR.
__global__ __launch_bounds__(256, 6) void k4_out(
    const unsigned short* __restrict__ expVT,
    const unsigned short* __restrict__ Gth, const unsigned short* __restrict__ Gtm,
    float* __restrict__ out)
{
    __shared__ unsigned short Vs[64 * 136];   // [n][i] pitch 136

    const int t = threadIdx.x;
    const int lane = t & 63, w = t >> 6;
    const int col16 = lane & 15, quad = lane >> 4;
    const int b = blockIdx.y, nb = blockIdx.x * 64;

#pragma unroll
    for (int it = 0; it < 4; ++it) {
        int idx = it * 256 + t;
        int n = idx >> 4, o = idx & 15;
        int o2 = (o + 4 * (n & 3)) & 15;
        *(uint4*)&Vs[n * 136 + o2 * 8] =
            *(const uint4*)&expVT[((size_t)b * HW_ + nb + n) * 128 + o2 * 8];
    }
    __syncthreads();

    f32x4 acc[8];
#pragma unroll
    for (int i = 0; i < 8; ++i) acc[i] = (f32x4){0.f,0.f,0.f,0.f};

    const unsigned short* gh = Gth + (size_t)b * 128 * 128;
    const unsigned short* gm = Gtm + (size_t)b * 128 * 128;

#pragma unroll
    for (int ks = 0; ks < 4; ++ks) {
        int ko = ks * 32 + quad * 8;
        bf16x8 vfr = *(const bf16x8*)&Vs[(w * 16 + col16) * 136 + ko];
#pragma unroll
        for (int mt = 0; mt < 8; ++mt) {
            int j = mt * 16 + col16;
            bf16x8 ah = *(const bf16x8*)&gh[j * 128 + ko];
            bf16x8 am = *(const bf16x8*)&gm[j * 128 + ko];
            acc[mt] = __builtin_amdgcn_mfma_f32_16x16x32_bf16(ah, vfr, acc[mt], 0, 0, 0);
            acc[mt] = __builtin_amdgcn_mfma_f32_16x16x32_bf16(am, vfr, acc[mt], 0, 0, 0);
        }
    }
    float* ob = out + (size_t)b * C_ * HW_;
#pragma unroll
    for (int mt = 0; mt < 8; ++mt)
#pragma unroll
        for (int r = 0; r < 4; ++r) {
            int j = mt * 16 + quad * 4 + r;
            int n = nb + w * 16 + col16;
            ob[(size_t)j * HW_ + n] = acc[mt][r];
        }
}

// ---------------------------------------------------------------------------
extern "C" void kernel_launch(void* const* d_in, const int* in_sizes, int n_in,
                              void* d_out, int out_size, void* d_ws, size_t ws_size,
                              hipStream_t stream)
{
    const float* x  = (const float*)d_in[0];
    const float* wA = (const float*)d_in[1];
    const float* bA = (const float*)d_in[2];
    const float* wB = (const float*)d_in[3];
    const float* bB = (const float*)d_in[4];
    const float* wV = (const float*)d_in[5];
    const float* bV = (const float*)d_in[6];
    float* out = (float*)d_out;

    // workspace (~69 MiB):
    //   Zcat 32K | Wh 64K | Wl 64K | expVT 32M | T_part 16*2M | G 2M
    char* ws = (char*)d_ws;
    float*          Zcat  = (float*)ws;                       // 32768
    unsigned short* Wh    = (unsigned short*)(ws + 32768);    // 65536
    unsigned short* Wl    = (unsigned short*)(ws + 98304);    // 65536
    unsigned short* expVT = (unsigned short*)(ws + 163840);   // 33554432
    float*          T_part= (float*)(ws + 33718272);          // 16*2097152
    unsigned short* Gth   = (unsigned short*)(ws + 33718272 + 16 * 2097152);
    unsigned short* Gtm   = Gth + 128 * 128 * 32;

    hipMemsetAsync(Zcat, 0, 32768, stream);   // Zcat only

    k0_prep <<<dim3(32),     256,  0, stream>>>(wB, wV, Wh, Wl);
    k1_fused<<<dim3(16, 32), 1024, 0, stream>>>(x, Wh, Wl, bB, bV, expVT, T_part, Zcat);
    k3b_G   <<<dim3(32, 32), 256,  0, stream>>>(T_part, wA, bA, Zcat, Gth, Gtm, 16);
    k4_out  <<<dim3(64, 32), 256,  0, stream>>>(expVT, Gth, Gtm, out);
}

// Round 8
// 208.446 us; speedup vs baseline: 1.2177x; 1.2177x over previous
//
#include <hip/hip_runtime.h>
#include <hip/hip_bf16.h>

// B=32, C=128, HW=4096.
//   E = [wB;wV]@x + bias ; expB/expV = exp(E) (bf16) ; ZB/ZV row sums
//   T[i,c] = sum_n expB[i,n]*x[c,n]
//   G[i,j] = ((T[i,:].wA[j,:])/ZB_i + bA[j]) / (4096*ZV_i)
//   out[j,n] = sum_i expV[i,n]*G[i,j]
// R8: fix the R7 tail regressions with counters in hand.
//   k4 (was 75us, MfmaUtil 4%, all pipes idle = L2-latency-bound G gather):
//     invert staging -- G (reused by all blocks of a b) goes to LDS once per
//     block (64KB, XOR-swizzled chunk^=j&15 for conflict-free b128), expV
//     (read exactly once) streams from global. 512 thr, grid(16,32)=2/CU.
//   k3b (was ~100us: 256MB T_part re-reads, 4x amplification from j-tiling):
//     k2b reduction reinstated (T_part->T once), k3b reads L2-hot T.
//   k1 frozen (72us, VGPR=64, no spill).

#define B_  32
#define C_  128
#define HW_ 4096

typedef __attribute__((ext_vector_type(8))) __bf16 bf16x8;
typedef __attribute__((ext_vector_type(4))) float f32x4;

__device__ __forceinline__ unsigned int bf_rne(float f) {   // bf16 bits (RNE)
    unsigned int u = __float_as_uint(f);
    return (u + 0x7fffu + ((u >> 16) & 1u)) >> 16;
}
__device__ __forceinline__ float bf_hi(float f) {           // RNE-to-bf16, as fp32
    unsigned int u = __float_as_uint(f);
    return __uint_as_float((u + 0x7fffu + ((u >> 16) & 1u)) & 0xffff0000u);
}

// ---------------------------------------------------------------------------
// k0: split Wcat=[wB;wV] (256x128 fp32) into bf16 hi/lo arrays. grid 32x256.
__global__ __launch_bounds__(256) void k0_prep(
    const float* __restrict__ wB, const float* __restrict__ wV,
    unsigned short* __restrict__ Wh, unsigned short* __restrict__ Wl)
{
    int g = blockIdx.x * 256 + threadIdx.x;      // 0..8191 float4s
    int row = g >> 5, c4 = (g & 31) << 2;
    const float* src = (row < 128) ? &wB[row * 128] : &wV[(row - 128) * 128];
    float4 v = *(const float4*)&src[c4];
    float vv[4] = {v.x, v.y, v.z, v.w};
    unsigned int h[4], l[4];
#pragma unroll
    for (int e = 0; e < 4; ++e) {
        float hf = bf_hi(vv[e]);
        h[e] = __float_as_uint(hf) >> 16;
        l[e] = bf_rne(vv[e] - hf);
    }
    *(uint2*)&Wh[row * 128 + c4] = make_uint2(h[0] | (h[1] << 16), h[2] | (h[3] << 16));
    *(uint2*)&Wl[row * 128 + c4] = make_uint2(l[0] | (l[1] << 16), l[2] | (l[3] << 16));
}

// ---------------------------------------------------------------------------
// k1_fused: E-GEMM + exp + Z + T-GEMM + expVT copy-out. grid (16, 32),
// 1024 thr = 16 waves. (frozen from R6: 72us, VGPR=64, no spill)
__global__ __launch_bounds__(1024, 1) void k1_fused(
    const float* __restrict__ x,
    const unsigned short* __restrict__ Wh, const unsigned short* __restrict__ Wl,
    const float* __restrict__ bB, const float* __restrict__ bV,
    unsigned short* __restrict__ expVT, float* __restrict__ T_part,
    float* __restrict__ Zcat)
{
    __shared__ unsigned short XT_h[32 * 136];   // [n][c] pitch 136 (E B-operand)
    __shared__ unsigned short XT_l[32 * 136];
    __shared__ unsigned short XN_h[128 * 40];   // [c][n] pitch 40 (T B-operand)
    __shared__ unsigned short XN_l[128 * 40];
    __shared__ unsigned short EBs[128 * 40];    // expB [i][n] pitch 40 (T A-operand)
    __shared__ unsigned short EVs[32 * 136];    // expV [n][i] pitch 136 (copy-out)
    __shared__ float bias_s[256];

    const int t = threadIdx.x;
    const int lane = t & 63, w = t >> 6;        // w = 0..15
    const int col16 = lane & 15, quad = lane >> 4;
    const int b = blockIdx.y;
    const int n0 = blockIdx.x * 256;
    const float* xb = x + (size_t)b * C_ * HW_;

    // staging pattern A (for XT): thread owns 4 c (cq0*4+cc) at one n (snA)
    const int snA = t & 31, cq0 = t >> 5;       // cq0 = 0..31
    // staging pattern B (for XN): thread owns 1 c row (scB), 4 n (sqB..+3)
    const int scB = t >> 3, sqB = (t & 7) * 4;

    const int rowbase = w * 16;                 // E rows for this wave (0..255)
    const int lbase = (w & 7) * 16;             // row base within 128-row projection
    const int boff = (w < 8) ? 0 : 128;
    const int mh = (w >> 3) * 64;               // T tile: i-half
    const int nh = (w & 7) * 16;                // T tile: c-sixteenth

    if (t < 256) bias_s[t] = (t < 128) ? bB[t] : bV[t - 128];

    f32x4 tacc[4];
    float zacc[4];
#pragma unroll
    for (int i = 0; i < 4; ++i) { tacc[i] = (f32x4){0.f,0.f,0.f,0.f}; zacc[i] = 0.f; }

    // prefetch subtile 0, both patterns
    float xrA[4], xrB[4];
#pragma unroll
    for (int cc = 0; cc < 4; ++cc)
        xrA[cc] = xb[(size_t)(cq0 * 4 + cc) * HW_ + n0 + snA];
    *(float4*)xrB = *(const float4*)&xb[(size_t)scB * HW_ + n0 + sqB];

    for (int st = 0; st < 8; ++st) {
        // convert pattern A (pre-barrier: overlaps wait)
        unsigned int ha[4], la[4];
#pragma unroll
        for (int e = 0; e < 4; ++e) {
            float hf = bf_hi(xrA[e]);
            ha[e] = __float_as_uint(hf) >> 16;
            la[e] = bf_rne(xrA[e] - hf);
        }
        __syncthreads();   // B1: previous subtile's T-GEMM reads / copy-out done
        *(uint2*)&XT_h[snA * 136 + cq0 * 4] = make_uint2(ha[0] | (ha[1] << 16), ha[2] | (ha[3] << 16));
        *(uint2*)&XT_l[snA * 136 + cq0 * 4] = make_uint2(la[0] | (la[1] << 16), la[2] | (la[3] << 16));
        {
            unsigned int hb[4], lb[4];
#pragma unroll
            for (int e = 0; e < 4; ++e) {
                float hf = bf_hi(xrB[e]);
                hb[e] = __float_as_uint(hf) >> 16;
                lb[e] = bf_rne(xrB[e] - hf);
            }
            *(uint2*)&XN_h[scB * 40 + sqB] = make_uint2(hb[0] | (hb[1] << 16), hb[2] | (hb[3] << 16));
            *(uint2*)&XN_l[scB * 40 + sqB] = make_uint2(lb[0] | (lb[1] << 16), lb[2] | (lb[3] << 16));
        }
        __syncthreads();   // B2: XT/XN visible
        // prefetch next subtile (overlaps E/T compute)
        if (st < 7) {
            int ns2 = n0 + (st + 1) * 32;
#pragma unroll
            for (int cc = 0; cc < 4; ++cc)
                xrA[cc] = xb[(size_t)(cq0 * 4 + cc) * HW_ + ns2 + snA];
            *(float4*)xrB = *(const float4*)&xb[(size_t)scB * HW_ + ns2 + sqB];
        }

        // --- E-GEMM: wave computes rows rowbase..+15 x 32 n, K=128 (c), 3 terms
        f32x4 e0 = (f32x4){0.f,0.f,0.f,0.f}, e1 = (f32x4){0.f,0.f,0.f,0.f};
#pragma unroll
        for (int ks = 0; ks < 4; ++ks) {
            int kc = ks * 32 + quad * 8;
            bf16x8 xh0 = *(const bf16x8*)&XT_h[col16 * 136 + kc];
            bf16x8 xl0 = *(const bf16x8*)&XT_l[col16 * 136 + kc];
            bf16x8 xh1 = *(const bf16x8*)&XT_h[(16 + col16) * 136 + kc];
            bf16x8 xl1 = *(const bf16x8*)&XT_l[(16 + col16) * 136 + kc];
            int row = rowbase + col16;
            bf16x8 wh = *(const bf16x8*)&Wh[row * 128 + kc];
            bf16x8 wl = *(const bf16x8*)&Wl[row * 128 + kc];
            e0 = __builtin_amdgcn_mfma_f32_16x16x32_bf16(wh, xh0, e0, 0, 0, 0);
            e0 = __builtin_amdgcn_mfma_f32_16x16x32_bf16(wh, xl0, e0, 0, 0, 0);
            e0 = __builtin_amdgcn_mfma_f32_16x16x32_bf16(wl, xh0, e0, 0, 0, 0);
            e1 = __builtin_amdgcn_mfma_f32_16x16x32_bf16(wh, xh1, e1, 0, 0, 0);
            e1 = __builtin_amdgcn_mfma_f32_16x16x32_bf16(wh, xl1, e1, 0, 0, 0);
            e1 = __builtin_amdgcn_mfma_f32_16x16x32_bf16(wl, xh1, e1, 0, 0, 0);
        }

        // --- epilogue: exp, Z accumulate, expB->EBs [i][n] / expV->EVs [n][i]
#pragma unroll
        for (int r = 0; r < 4; ++r) {
            int lrow = lbase + quad * 4 + r;     // 0..127 within projection
            float bb = bias_s[boff + lrow];
            float v0 = __expf(e0[r] + bb);
            float v1 = __expf(e1[r] + bb);
            zacc[r] += v0 + v1;
            if (w < 8) {
                EBs[lrow * 40 + col16]      = (unsigned short)bf_rne(v0);
                EBs[lrow * 40 + 16 + col16] = (unsigned short)bf_rne(v1);
            } else {
                EVs[col16 * 136 + lrow]        = (unsigned short)bf_rne(v0);
                EVs[(16 + col16) * 136 + lrow] = (unsigned short)bf_rne(v1);
            }
        }
        __syncthreads();   // B3: EBs/EVs ready (XN still valid from B2)

        // --- T-GEMM: K=32 (this subtile), wave tile 64 i x 16 c
        {
            int c = nh + col16;
            bf16x8 bh = *(const bf16x8*)&XN_h[c * 40 + quad * 8];
            bf16x8 bl = *(const bf16x8*)&XN_l[c * 40 + quad * 8];
#pragma unroll
            for (int mt = 0; mt < 4; ++mt) {
                bf16x8 a = *(const bf16x8*)&EBs[(mh + mt * 16 + col16) * 40 + quad * 8];
                tacc[mt] = __builtin_amdgcn_mfma_f32_16x16x32_bf16(a, bh, tacc[mt], 0, 0, 0);
                tacc[mt] = __builtin_amdgcn_mfma_f32_16x16x32_bf16(a, bl, tacc[mt], 0, 0, 0);
            }
        }
        // --- expVT copy-out (32 n x 128 i), one uint2 (4 bf16) per thread
        {
            int nl = t >> 5, io = (t & 31) * 4;
            *(uint2*)&expVT[((size_t)b * HW_ + n0 + st * 32 + nl) * 128 + io] =
                *(const uint2*)&EVs[nl * 136 + io];
        }
    }

    // T_part store (no atomics): chunk = blockIdx.x
    float* Tp = T_part + (((size_t)blockIdx.x * B_) + b) * 128 * 128;
#pragma unroll
    for (int mt = 0; mt < 4; ++mt)
#pragma unroll
        for (int r = 0; r < 4; ++r)
            Tp[(mh + mt * 16 + quad * 4 + r) * 128 + nh + col16] = tacc[mt][r];

    // Z atomics (one per row, reduced across col16 lanes first)
#pragma unroll
    for (int r = 0; r < 4; ++r) {
        float rs = zacc[r];
        rs += __shfl_xor(rs, 1, 16);
        rs += __shfl_xor(rs, 2, 16);
        rs += __shfl_xor(rs, 4, 16);
        rs += __shfl_xor(rs, 8, 16);
        if (col16 == 0)
            atomicAdd(&Zcat[b * 256 + boff + lbase + quad * 4 + r], rs);
    }
}

// ---------------------------------------------------------------------------
// k2b: T = sum_p T_part[p]. grid 512, 256 thr, one float4 per thread.
__global__ __launch_bounds__(256) void k2b_red(
    const float* __restrict__ T_part, float* __restrict__ T)
{
    int g = blockIdx.x * 256 + threadIdx.x;     // 0..131071
    size_t o = (size_t)g * 4;
    float4 s = make_float4(0.f, 0.f, 0.f, 0.f);
#pragma unroll
    for (int p = 0; p < 16; ++p) {
        float4 v = *(const float4*)&T_part[(size_t)p * (B_ * 128 * 128) + o];
        s.x += v.x; s.y += v.y; s.z += v.z; s.w += v.w;
    }
    *(float4*)&T[o] = s;
}

// ---------------------------------------------------------------------------
// k3b: G transposed + 2-way bf16 split, reading reduced T (L2-hot, 2MB).
// grid (32, 32) = 1024 blocks, 256 thr. Tiles 16 j x 32 i.
__global__ __launch_bounds__(256) void k3b_G(
    const float* __restrict__ T, const float* __restrict__ wA,
    const float* __restrict__ bA, const float* __restrict__ Zcat,
    unsigned short* __restrict__ Gth, unsigned short* __restrict__ Gtm)
{
    const int t = threadIdx.x;
    const int tx = t & 15, ty = t >> 4;
    const int b = blockIdx.y;
    const int jb = (blockIdx.x >> 2) * 16;     // 8 j-tiles of 16
    const int ib = (blockIdx.x & 3) * 32;      // 4 i-tiles of 32

    __shared__ float Ts[32][36];
    __shared__ float Wa[16][36];

    float acc[2] = {0.f, 0.f};

    for (int c0 = 0; c0 < 128; c0 += 32) {
        __syncthreads();
        {
            int r = t >> 3, kq = (t & 7) << 2;
            *(float4*)&Ts[r][kq] = *(const float4*)&T[((size_t)b * 128 + ib + r) * 128 + c0 + kq];
        }
        if (t < 128) {
            int r = t >> 3, kq = (t & 7) << 2;
            *(float4*)&Wa[r][kq] = *(const float4*)&wA[(jb + r) * 128 + c0 + kq];
        }
        __syncthreads();
#pragma unroll
        for (int k = 0; k < 32; k += 4) {
            float4 wv  = *(const float4*)&Wa[ty][k];
            float4 tv0 = *(const float4*)&Ts[tx][k];
            float4 tv1 = *(const float4*)&Ts[16 + tx][k];
            acc[0] = fmaf(wv.x, tv0.x, acc[0]);
            acc[0] = fmaf(wv.y, tv0.y, acc[0]);
            acc[0] = fmaf(wv.z, tv0.z, acc[0]);
            acc[0] = fmaf(wv.w, tv0.w, acc[0]);
            acc[1] = fmaf(wv.x, tv1.x, acc[1]);
            acc[1] = fmaf(wv.y, tv1.y, acc[1]);
            acc[1] = fmaf(wv.z, tv1.z, acc[1]);
            acc[1] = fmaf(wv.w, tv1.w, acc[1]);
        }
    }
    const float* ZB = Zcat + b * 256;
    const float* ZV = ZB + 128;
    {
        int j = jb + ty;
        float bj = bA[j];
#pragma unroll
        for (int ii = 0; ii < 2; ++ii) {
            int i = ib + ii * 16 + tx;
            float g = (acc[ii] / ZB[i] + bj) / (4096.f * ZV[i]);
            float h = bf_hi(g);  float r1 = g - h;
            float m = bf_hi(r1);
            size_t o = ((size_t)b * 128 + j) * 128 + i;
            Gth[o] = (unsigned short)(__float_as_uint(h) >> 16);
            Gtm[o] = (unsigned short)(__float_as_uint(m) >> 16);
        }
    }
}

// ---------------------------------------------------------------------------
// k4: out[b,j,n] = sum_i expVT[n][i] * Gt(j,i). G staged in LDS (64KB,
// XOR-swizzled), expV streamed from global. grid (16, 32), 512 thr = 8 waves.
__global__ __launch_bounds__(512, 2) void k4_out(
    const unsigned short* __restrict__ expVT,
    const unsigned short* __restrict__ Gth, const unsigned short* __restrict__ Gtm,
    float* __restrict__ out)
{
    __shared__ unsigned short Gs_h[128 * 128];   // [j][i], 16B-chunk ^= (j&15)
    __shared__ unsigned short Gs_m[128 * 128];

    const int t = threadIdx.x;
    const int lane = t & 63, w = t >> 6;         // w = 0..7
    const int col16 = lane & 15, quad = lane >> 4;
    const int b = blockIdx.y, nb = blockIdx.x * 256;

    const unsigned short* gh = Gth + (size_t)b * 128 * 128;
    const unsigned short* gm = Gtm + (size_t)b * 128 * 128;

    // stage G: 2048 uint4 per array, 4 per thread, swizzled chunk = o ^ (j&15)
#pragma unroll
    for (int it = 0; it < 4; ++it) {
        int idx = it * 512 + t;
        int j = idx >> 4, o = idx & 15;
        int od = (o ^ (j & 15)) << 3;            // halfword offset of swizzled chunk
        *(uint4*)&Gs_h[j * 128 + od] = *(const uint4*)&gh[j * 128 + (o << 3)];
        *(uint4*)&Gs_m[j * 128 + od] = *(const uint4*)&gm[j * 128 + (o << 3)];
    }
    __syncthreads();

    f32x4 acc[8][2];
#pragma unroll
    for (int i = 0; i < 8; ++i)
#pragma unroll
        for (int j = 0; j < 2; ++j) acc[i][j] = (f32x4){0.f,0.f,0.f,0.f};

#pragma unroll
    for (int ks = 0; ks < 4; ++ks) {
        bf16x8 vfr[2];
#pragma unroll
        for (int nt = 0; nt < 2; ++nt) {
            int n = nb + w * 32 + nt * 16 + col16;
            vfr[nt] = *(const bf16x8*)&expVT[((size_t)b * HW_ + n) * 128 + ks * 32 + quad * 8];
        }
        int pc = ((ks * 4 + quad) ^ col16) << 3; // swizzled chunk offset (j&15 == col16)
#pragma unroll
        for (int mt = 0; mt < 8; ++mt) {
            int j = mt * 16 + col16;
            bf16x8 ah = *(const bf16x8*)&Gs_h[j * 128 + pc];
            bf16x8 am = *(const bf16x8*)&Gs_m[j * 128 + pc];
#pragma unroll
            for (int nt = 0; nt < 2; ++nt) {
                acc[mt][nt] = __builtin_amdgcn_mfma_f32_16x16x32_bf16(ah, vfr[nt], acc[mt][nt], 0, 0, 0);
                acc[mt][nt] = __builtin_amdgcn_mfma_f32_16x16x32_bf16(am, vfr[nt], acc[mt][nt], 0, 0, 0);
            }
        }
    }
    float* ob = out + (size_t)b * C_ * HW_;
#pragma unroll
    for (int mt = 0; mt < 8; ++mt)
#pragma unroll
        for (int nt = 0; nt < 2; ++nt)
#pragma unroll
            for (int r = 0; r < 4; ++r) {
                int j = mt * 16 + quad * 4 + r;
                int n = nb + w * 32 + nt * 16 + col16;
                ob[(size_t)j * HW_ + n] = acc[mt][nt][r];
            }
}

// ---------------------------------------------------------------------------
extern "C" void kernel_launch(void* const* d_in, const int* in_sizes, int n_in,
                              void* d_out, int out_size, void* d_ws, size_t ws_size,
                              hipStream_t stream)
{
    const float* x  = (const float*)d_in[0];
    const float* wA = (const float*)d_in[1];
    const float* bA = (const float*)d_in[2];
    const float* wB = (const float*)d_in[3];
    const float* bB = (const float*)d_in[4];
    const float* wV = (const float*)d_in[5];
    const float* bV = (const float*)d_in[6];
    float* out = (float*)d_out;

    // workspace (~69 MiB):
    //   Zcat 32K | Wh 64K | Wl 64K | expVT 32M | T_part 32M | T 2M | G 2M
    char* ws = (char*)d_ws;
    float*          Zcat  = (float*)ws;                       // 32768
    unsigned short* Wh    = (unsigned short*)(ws + 32768);    // 65536
    unsigned short* Wl    = (unsigned short*)(ws + 98304);    // 65536
    unsigned short* expVT = (unsigned short*)(ws + 163840);   // 33554432
    float*          T_part= (float*)(ws + 33718272);          // 33554432
    float*          T     = (float*)(ws + 67272704);          // 2097152
    unsigned short* Gth   = (unsigned short*)(ws + 69369856); // 1048576
    unsigned short* Gtm   = Gth + 128 * 128 * 32;             // 1048576

    hipMemsetAsync(Zcat, 0, 32768, stream);   // Zcat only

    k0_prep <<<dim3(32),     256,  0, stream>>>(wB, wV, Wh, Wl);
    k1_fused<<<dim3(16, 32), 1024, 0, stream>>>(x, Wh, Wl, bB, bV, expVT, T_part, Zcat);
    k2b_red <<<dim3(512),    256,  0, stream>>>(T_part, T);
    k3b_G   <<<dim3(32, 32), 256,  0, stream>>>(T, wA, bA, Zcat, Gth, Gtm);
    k4_out  <<<dim3(16, 32), 512,  0, stream>>>(expVT, Gth, Gtm, out);
}

// Round 9
// 205.304 us; speedup vs baseline: 1.2363x; 1.0153x over previous
//
#include <hip/hip_runtime.h>
#include <hip/hip_bf16.h>

// B=32, C=128, HW=4096.
//   E = [wB;wV]@x + bias ; expB/expV = exp(E) (bf16) ; ZB/ZV row sums
//   T[i,c] = sum_n expB[i,n]*x[c,n]
//   G[i,j] = ((T[i,:].wA[j,:])/ZB_i + bA[j]) / (4096*ZV_i)
//   out[j,n] = sum_i expV[i,n]*G[i,j]
// R9: single-variable round -- k1 (1024,1) -> (1024,2). R8 counters: k1 at
//   38.7% occupancy (1 block/CU promised by the bound) though LDS (57.9KBx2
//   <=160KB) and VGPR (64x32 waves = full file) both permit 2 blocks/CU.
//   Compiler already allocates 64 regs under a 128 cap, so the implied 64-reg
//   cap is a no-op (no R2/R4 spill risk). 2 resident blocks let one block's
//   waves cover the other's barrier drains (3 barriers x 8 subtiles).
//   Everything else frozen from R8 (208us: k4 LDS-G inversion, k2b/k3b).

#define B_  32
#define C_  128
#define HW_ 4096

typedef __attribute__((ext_vector_type(8))) __bf16 bf16x8;
typedef __attribute__((ext_vector_type(4))) float f32x4;

__device__ __forceinline__ unsigned int bf_rne(float f) {   // bf16 bits (RNE)
    unsigned int u = __float_as_uint(f);
    return (u + 0x7fffu + ((u >> 16) & 1u)) >> 16;
}
__device__ __forceinline__ float bf_hi(float f) {           // RNE-to-bf16, as fp32
    unsigned int u = __float_as_uint(f);
    return __uint_as_float((u + 0x7fffu + ((u >> 16) & 1u)) & 0xffff0000u);
}

// ---------------------------------------------------------------------------
// k0: split Wcat=[wB;wV] (256x128 fp32) into bf16 hi/lo arrays. grid 32x256.
__global__ __launch_bounds__(256) void k0_prep(
    const float* __restrict__ wB, const float* __restrict__ wV,
    unsigned short* __restrict__ Wh, unsigned short* __restrict__ Wl)
{
    int g = blockIdx.x * 256 + threadIdx.x;      // 0..8191 float4s
    int row = g >> 5, c4 = (g & 31) << 2;
    const float* src = (row < 128) ? &wB[row * 128] : &wV[(row - 128) * 128];
    float4 v = *(const float4*)&src[c4];
    float vv[4] = {v.x, v.y, v.z, v.w};
    unsigned int h[4], l[4];
#pragma unroll
    for (int e = 0; e < 4; ++e) {
        float hf = bf_hi(vv[e]);
        h[e] = __float_as_uint(hf) >> 16;
        l[e] = bf_rne(vv[e] - hf);
    }
    *(uint2*)&Wh[row * 128 + c4] = make_uint2(h[0] | (h[1] << 16), h[2] | (h[3] << 16));
    *(uint2*)&Wl[row * 128 + c4] = make_uint2(l[0] | (l[1] << 16), l[2] | (l[3] << 16));
}

// ---------------------------------------------------------------------------
// k1_fused: E-GEMM + exp + Z + T-GEMM + expVT copy-out. grid (16, 32),
// 1024 thr = 16 waves, (1024,2) => 2 blocks/CU = 32 waves/CU, cap 64 VGPR
// (= current natural allocation).
__global__ __launch_bounds__(1024, 2) void k1_fused(
    const float* __restrict__ x,
    const unsigned short* __restrict__ Wh, const unsigned short* __restrict__ Wl,
    const float* __restrict__ bB, const float* __restrict__ bV,
    unsigned short* __restrict__ expVT, float* __restrict__ T_part,
    float* __restrict__ Zcat)
{
    __shared__ unsigned short XT_h[32 * 136];   // [n][c] pitch 136 (E B-operand)
    __shared__ unsigned short XT_l[32 * 136];
    __shared__ unsigned short XN_h[128 * 40];   // [c][n] pitch 40 (T B-operand)
    __shared__ unsigned short XN_l[128 * 40];
    __shared__ unsigned short EBs[128 * 40];    // expB [i][n] pitch 40 (T A-operand)
    __shared__ unsigned short EVs[32 * 136];    // expV [n][i] pitch 136 (copy-out)
    __shared__ float bias_s[256];

    const int t = threadIdx.x;
    const int lane = t & 63, w = t >> 6;        // w = 0..15
    const int col16 = lane & 15, quad = lane >> 4;
    const int b = blockIdx.y;
    const int n0 = blockIdx.x * 256;
    const float* xb = x + (size_t)b * C_ * HW_;

    // staging pattern A (for XT): thread owns 4 c (cq0*4+cc) at one n (snA)
    const int snA = t & 31, cq0 = t >> 5;       // cq0 = 0..31
    // staging pattern B (for XN): thread owns 1 c row (scB), 4 n (sqB..+3)
    const int scB = t >> 3, sqB = (t & 7) * 4;

    const int rowbase = w * 16;                 // E rows for this wave (0..255)
    const int lbase = (w & 7) * 16;             // row base within 128-row projection
    const int boff = (w < 8) ? 0 : 128;
    const int mh = (w >> 3) * 64;               // T tile: i-half
    const int nh = (w & 7) * 16;                // T tile: c-sixteenth

    if (t < 256) bias_s[t] = (t < 128) ? bB[t] : bV[t - 128];

    f32x4 tacc[4];
    float zacc[4];
#pragma unroll
    for (int i = 0; i < 4; ++i) { tacc[i] = (f32x4){0.f,0.f,0.f,0.f}; zacc[i] = 0.f; }

    // prefetch subtile 0, both patterns
    float xrA[4], xrB[4];
#pragma unroll
    for (int cc = 0; cc < 4; ++cc)
        xrA[cc] = xb[(size_t)(cq0 * 4 + cc) * HW_ + n0 + snA];
    *(float4*)xrB = *(const float4*)&xb[(size_t)scB * HW_ + n0 + sqB];

    for (int st = 0; st < 8; ++st) {
        // convert pattern A (pre-barrier: overlaps wait)
        unsigned int ha[4], la[4];
#pragma unroll
        for (int e = 0; e < 4; ++e) {
            float hf = bf_hi(xrA[e]);
            ha[e] = __float_as_uint(hf) >> 16;
            la[e] = bf_rne(xrA[e] - hf);
        }
        __syncthreads();   // B1: previous subtile's T-GEMM reads / copy-out done
        *(uint2*)&XT_h[snA * 136 + cq0 * 4] = make_uint2(ha[0] | (ha[1] << 16), ha[2] | (ha[3] << 16));
        *(uint2*)&XT_l[snA * 136 + cq0 * 4] = make_uint2(la[0] | (la[1] << 16), la[2] | (la[3] << 16));
        {
            unsigned int hb[4], lb[4];
#pragma unroll
            for (int e = 0; e < 4; ++e) {
                float hf = bf_hi(xrB[e]);
                hb[e] = __float_as_uint(hf) >> 16;
                lb[e] = bf_rne(xrB[e] - hf);
            }
            *(uint2*)&XN_h[scB * 40 + sqB] = make_uint2(hb[0] | (hb[1] << 16), hb[2] | (hb[3] << 16));
            *(uint2*)&XN_l[scB * 40 + sqB] = make_uint2(lb[0] | (lb[1] << 16), lb[2] | (lb[3] << 16));
        }
        __syncthreads();   // B2: XT/XN visible
        // prefetch next subtile (overlaps E/T compute)
        if (st < 7) {
            int ns2 = n0 + (st + 1) * 32;
#pragma unroll
            for (int cc = 0; cc < 4; ++cc)
                xrA[cc] = xb[(size_t)(cq0 * 4 + cc) * HW_ + ns2 + snA];
            *(float4*)xrB = *(const float4*)&xb[(size_t)scB * HW_ + ns2 + sqB];
        }

        // --- E-GEMM: wave computes rows rowbase..+15 x 32 n, K=128 (c), 3 terms
        f32x4 e0 = (f32x4){0.f,0.f,0.f,0.f}, e1 = (f32x4){0.f,0.f,0.f,0.f};
#pragma unroll
        for (int ks = 0; ks < 4; ++ks) {
            int kc = ks * 32 + quad * 8;
            bf16x8 xh0 = *(const bf16x8*)&XT_h[col16 * 136 + kc];
            bf16x8 xl0 = *(const bf16x8*)&XT_l[col16 * 136 + kc];
            bf16x8 xh1 = *(const bf16x8*)&XT_h[(16 + col16) * 136 + kc];
            bf16x8 xl1 = *(const bf16x8*)&XT_l[(16 + col16) * 136 + kc];
            int row = rowbase + col16;
            bf16x8 wh = *(const bf16x8*)&Wh[row * 128 + kc];
            bf16x8 wl = *(const bf16x8*)&Wl[row * 128 + kc];
            e0 = __builtin_amdgcn_mfma_f32_16x16x32_bf16(wh, xh0, e0, 0, 0, 0);
            e0 = __builtin_amdgcn_mfma_f32_16x16x32_bf16(wh, xl0, e0, 0, 0, 0);
            e0 = __builtin_amdgcn_mfma_f32_16x16x32_bf16(wl, xh0, e0, 0, 0, 0);
            e1 = __builtin_amdgcn_mfma_f32_16x16x32_bf16(wh, xh1, e1, 0, 0, 0);
            e1 = __builtin_amdgcn_mfma_f32_16x16x32_bf16(wh, xl1, e1, 0, 0, 0);
            e1 = __builtin_amdgcn_mfma_f32_16x16x32_bf16(wl, xh1, e1, 0, 0, 0);
        }

        // --- epilogue: exp, Z accumulate, expB->EBs [i][n] / expV->EVs [n][i]
#pragma unroll
        for (int r = 0; r < 4; ++r) {
            int lrow = lbase + quad * 4 + r;     // 0..127 within projection
            float bb = bias_s[boff + lrow];
            float v0 = __expf(e0[r] + bb);
            float v1 = __expf(e1[r] + bb);
            zacc[r] += v0 + v1;
            if (w < 8) {
                EBs[lrow * 40 + col16]      = (unsigned short)bf_rne(v0);
                EBs[lrow * 40 + 16 + col16] = (unsigned short)bf_rne(v1);
            } else {
                EVs[col16 * 136 + lrow]        = (unsigned short)bf_rne(v0);
                EVs[(16 + col16) * 136 + lrow] = (unsigned short)bf_rne(v1);
            }
        }
        __syncthreads();   // B3: EBs/EVs ready (XN still valid from B2)

        // --- T-GEMM: K=32 (this subtile), wave tile 64 i x 16 c
        {
            int c = nh + col16;
            bf16x8 bh = *(const bf16x8*)&XN_h[c * 40 + quad * 8];
            bf16x8 bl = *(const bf16x8*)&XN_l[c * 40 + quad * 8];
#pragma unroll
            for (int mt = 0; mt < 4; ++mt) {
                bf16x8 a = *(const bf16x8*)&EBs[(mh + mt * 16 + col16) * 40 + quad * 8];
                tacc[mt] = __builtin_amdgcn_mfma_f32_16x16x32_bf16(a, bh, tacc[mt], 0, 0, 0);
                tacc[mt] = __builtin_amdgcn_mfma_f32_16x16x32_bf16(a, bl, tacc[mt], 0, 0, 0);
            }
        }
        // --- expVT copy-out (32 n x 128 i), one uint2 (4 bf16) per thread
        {
            int nl = t >> 5, io = (t & 31) * 4;
            *(uint2*)&expVT[((size_t)b * HW_ + n0 + st * 32 + nl) * 128 + io] =
                *(const uint2*)&EVs[nl * 136 + io];
        }
    }

    // T_part store (no atomics): chunk = blockIdx.x
    float* Tp = T_part + (((size_t)blockIdx.x * B_) + b) * 128 * 128;
#pragma unroll
    for (int mt = 0; mt < 4; ++mt)
#pragma unroll
        for (int r = 0; r < 4; ++r)
            Tp[(mh + mt * 16 + quad * 4 + r) * 128 + nh + col16] = tacc[mt][r];

    // Z atomics (one per row, reduced across col16 lanes first)
#pragma unroll
    for (int r = 0; r < 4; ++r) {
        float rs = zacc[r];
        rs += __shfl_xor(rs, 1, 16);
        rs += __shfl_xor(rs, 2, 16);
        rs += __shfl_xor(rs, 4, 16);
        rs += __shfl_xor(rs, 8, 16);
        if (col16 == 0)
            atomicAdd(&Zcat[b * 256 + boff + lbase + quad * 4 + r], rs);
    }
}

// ---------------------------------------------------------------------------
// k2b: T = sum_p T_part[p]. grid 512, 256 thr, one float4 per thread.
__global__ __launch_bounds__(256) void k2b_red(
    const float* __restrict__ T_part, float* __restrict__ T)
{
    int g = blockIdx.x * 256 + threadIdx.x;     // 0..131071
    size_t o = (size_t)g * 4;
    float4 s = make_float4(0.f, 0.f, 0.f, 0.f);
#pragma unroll
    for (int p = 0; p < 16; ++p) {
        float4 v = *(const float4*)&T_part[(size_t)p * (B_ * 128 * 128) + o];
        s.x += v.x; s.y += v.y; s.z += v.z; s.w += v.w;
    }
    *(float4*)&T[o] = s;
}

// ---------------------------------------------------------------------------
// k3b: G transposed + 2-way bf16 split, reading reduced T (L2-hot, 2MB).
// grid (32, 32) = 1024 blocks, 256 thr. Tiles 16 j x 32 i.
__global__ __launch_bounds__(256) void k3b_G(
    const float* __restrict__ T, const float* __restrict__ wA,
    const float* __restrict__ bA, const float* __restrict__ Zcat,
    unsigned short* __restrict__ Gth, unsigned short* __restrict__ Gtm)
{
    const int t = threadIdx.x;
    const int tx = t & 15, ty = t >> 4;
    const int b = blockIdx.y;
    const int jb = (blockIdx.x >> 2) * 16;     // 8 j-tiles of 16
    const int ib = (blockIdx.x & 3) * 32;      // 4 i-tiles of 32

    __shared__ float Ts[32][36];
    __shared__ float Wa[16][36];

    float acc[2] = {0.f, 0.f};

    for (int c0 = 0; c0 < 128; c0 += 32) {
        __syncthreads();
        {
            int r = t >> 3, kq = (t & 7) << 2;
            *(float4*)&Ts[r][kq] = *(const float4*)&T[((size_t)b * 128 + ib + r) * 128 + c0 + kq];
        }
        if (t < 128) {
            int r = t >> 3, kq = (t & 7) << 2;
            *(float4*)&Wa[r][kq] = *(const float4*)&wA[(jb + r) * 128 + c0 + kq];
        }
        __syncthreads();
#pragma unroll
        for (int k = 0; k < 32; k += 4) {
            float4 wv  = *(const float4*)&Wa[ty][k];
            float4 tv0 = *(const float4*)&Ts[tx][k];
            float4 tv1 = *(const float4*)&Ts[16 + tx][k];
            acc[0] = fmaf(wv.x, tv0.x, acc[0]);
            acc[0] = fmaf(wv.y, tv0.y, acc[0]);
            acc[0] = fmaf(wv.z, tv0.z, acc[0]);
            acc[0] = fmaf(wv.w, tv0.w, acc[0]);
            acc[1] = fmaf(wv.x, tv1.x, acc[1]);
            acc[1] = fmaf(wv.y, tv1.y, acc[1]);
            acc[1] = fmaf(wv.z, tv1.z, acc[1]);
            acc[1] = fmaf(wv.w, tv1.w, acc[1]);
        }
    }
    const float* ZB = Zcat + b * 256;
    const float* ZV = ZB + 128;
    {
        int j = jb + ty;
        float bj = bA[j];
#pragma unroll
        for (int ii = 0; ii < 2; ++ii) {
            int i = ib + ii * 16 + tx;
            float g = (acc[ii] / ZB[i] + bj) / (4096.f * ZV[i]);
            float h = bf_hi(g);  float r1 = g - h;
            float m = bf_hi(r1);
            size_t o = ((size_t)b * 128 + j) * 128 + i;
            Gth[o] = (unsigned short)(__float_as_uint(h) >> 16);
            Gtm[o] = (unsigned short)(__float_as_uint(m) >> 16);
        }
    }
}

// ---------------------------------------------------------------------------
// k4: out[b,j,n] = sum_i expVT[n][i] * Gt(j,i). G staged in LDS (64KB,
// XOR-swizzled), expV streamed from global. grid (16, 32), 512 thr = 8 waves.
__global__ __launch_bounds__(512, 2) void k4_out(
    const unsigned short* __restrict__ expVT,
    const unsigned short* __restrict__ Gth, const unsigned short* __restrict__ Gtm,
    float* __restrict__ out)
{
    __shared__ unsigned short Gs_h[128 * 128];   // [j][i], 16B-chunk ^= (j&15)
    __shared__ unsigned short Gs_m[128 * 128];

    const int t = threadIdx.x;
    const int lane = t & 63, w = t >> 6;         // w = 0..7
    const int col16 = lane & 15, quad = lane >> 4;
    const int b = blockIdx.y, nb = blockIdx.x * 256;

    const unsigned short* gh = Gth + (size_t)b * 128 * 128;
    const unsigned short* gm = Gtm + (size_t)b * 128 * 128;

    // stage G: 2048 uint4 per array, 4 per thread, swizzled chunk = o ^ (j&15)
#pragma unroll
    for (int it = 0; it < 4; ++it) {
        int idx = it * 512 + t;
        int j = idx >> 4, o = idx & 15;
        int od = (o ^ (j & 15)) << 3;            // halfword offset of swizzled chunk
        *(uint4*)&Gs_h[j * 128 + od] = *(const uint4*)&gh[j * 128 + (o << 3)];
        *(uint4*)&Gs_m[j * 128 + od] = *(const uint4*)&gm[j * 128 + (o << 3)];
    }
    __syncthreads();

    f32x4 acc[8][2];
#pragma unroll
    for (int i = 0; i < 8; ++i)
#pragma unroll
        for (int j = 0; j < 2; ++j) acc[i][j] = (f32x4){0.f,0.f,0.f,0.f};

#pragma unroll
    for (int ks = 0; ks < 4; ++ks) {
        bf16x8 vfr[2];
#pragma unroll
        for (int nt = 0; nt < 2; ++nt) {
            int n = nb + w * 32 + nt * 16 + col16;
            vfr[nt] = *(const bf16x8*)&expVT[((size_t)b * HW_ + n) * 128 + ks * 32 + quad * 8];
        }
        int pc = ((ks * 4 + quad) ^ col16) << 3; // swizzled chunk offset (j&15 == col16)
#pragma unroll
        for (int mt = 0; mt < 8; ++mt) {
            int j = mt * 16 + col16;
            bf16x8 ah = *(const bf16x8*)&Gs_h[j * 128 + pc];
            bf16x8 am = *(const bf16x8*)&Gs_m[j * 128 + pc];
#pragma unroll
            for (int nt = 0; nt < 2; ++nt) {
                acc[mt][nt] = __builtin_amdgcn_mfma_f32_16x16x32_bf16(ah, vfr[nt], acc[mt][nt], 0, 0, 0);
                acc[mt][nt] = __builtin_amdgcn_mfma_f32_16x16x32_bf16(am, vfr[nt], acc[mt][nt], 0, 0, 0);
            }
        }
    }
    float* ob = out + (size_t)b * C_ * HW_;
#pragma unroll
    for (int mt = 0; mt < 8; ++mt)
#pragma unroll
        for (int nt = 0; nt < 2; ++nt)
#pragma unroll
            for (int r = 0; r < 4; ++r) {
                int j = mt * 16 + quad * 4 + r;
                int n = nb + w * 32 + nt * 16 + col16;
                ob[(size_t)j * HW_ + n] = acc[mt][nt][r];
            }
}

// ---------------------------------------------------------------------------
extern "C" void kernel_launch(void* const* d_in, const int* in_sizes, int n_in,
                              void* d_out, int out_size, void* d_ws, size_t ws_size,
                              hipStream_t stream)
{
    const float* x  = (const float*)d_in[0];
    const float* wA = (const float*)d_in[1];
    const float* bA = (const float*)d_in[2];
    const float* wB = (const float*)d_in[3];
    const float* bB = (const float*)d_in[4];
    const float* wV = (const float*)d_in[5];
    const float* bV = (const float*)d_in[6];
    float* out = (float*)d_out;

    // workspace (~69 MiB):
    //   Zcat 32K | Wh 64K | Wl 64K | expVT 32M | T_part 32M | T 2M | G 2M
    char* ws = (char*)d_ws;
    float*          Zcat  = (float*)ws;                       // 32768
    unsigned short* Wh    = (unsigned short*)(ws + 32768);    // 65536
    unsigned short* Wl    = (unsigned short*)(ws + 98304);    // 65536
    unsigned short* expVT = (unsigned short*)(ws + 163840);   // 33554432
    float*          T_part= (float*)(ws + 33718272);          // 33554432
    float*          T     = (float*)(ws + 67272704);          // 2097152
    unsigned short* Gth   = (unsigned short*)(ws + 69369856); // 1048576
    unsigned short* Gtm   = Gth + 128 * 128 * 32;             // 1048576

    hipMemsetAsync(Zcat, 0, 32768, stream);   // Zcat only

    k0_prep <<<dim3(32),     256,  0, stream>>>(wB, wV, Wh, Wl);
    k1_fused<<<dim3(16, 32), 1024, 0, stream>>>(x, Wh, Wl, bB, bV, expVT, T_part, Zcat);
    k2b_red <<<dim3(512),    256,  0, stream>>>(T_part, T);
    k3b_G   <<<dim3(32, 32), 256,  0, stream>>>(T, wA, bA, Zcat, Gth, Gtm);
    k4_out  <<<dim3(16, 32), 512,  0, stream>>>(expVT, Gth, Gtm, out);
}